// Round 6
// baseline (56.490 us; speedup 1.0000x reference)
//
#include <hip/hip_runtime.h>
#include <math.h>

#define N1 10000
#define N2 5000
#define DIN 30
#define DZ 32
#define N1P 10016   // 313*32
#define N2P 5024    // 157*32
#define NTJ 313     // j-tiles of 32
#define NTI 157     // i-tiles of 32
#define NCHB 16     // partial buffers per i-tile (blocks per i-tile)
#define CTILES 5    // j-tiles per wave-chunk (64 chunks; chunk62 has 3, 63 empty)
#define NRED 16     // landmark-reduction blocks

// byte offsets in ws (16B aligned)
#define OFFB_K    0u        // bf16 K[N1P][32]
#define OFFB_FZ   641024u   // bf16 Fz[32][N1P]  (z-major features)
#define OFFB_Q    1282048u  // bf16 Qs[N2P][32]  (pre-scaled by log2e/sqrt(32))
#define OFFB_ZP   1603584u  // f32 Zpart[16][N2P] (sum of em1)
#define OFFB_M1   1925120u  // bf16 M1part[16][N2P][32]
#define OFFB_RP   7069696u  // f32 red_part[16][66]: rsum[32],dvec[32],ds_sum

typedef __bf16 bf16x8 __attribute__((ext_vector_type(8)));
typedef float f32x16 __attribute__((ext_vector_type(16)));
typedef unsigned u32x2 __attribute__((ext_vector_type(2)));

union W4 { unsigned w[4]; bf16x8 v; };

__device__ __forceinline__ float softplus_f(float x) {
  return fmaxf(x, 0.f) + log1pf(__expf(-fabsf(x)));
}
__device__ __forceinline__ unsigned pack2bf(float a, float b) {
  union { __bf16 h[2]; unsigned u; } x;
  x.h[0] = (__bf16)a; x.h[1] = (__bf16)b; return x.u;
}

// Fused prep. blocks [0,157): K+Fz (64 lm rows each); [157,236): Q (64 tg rows);
// [236,252): landmark reductions -> red_part (no atomics).
__global__ __launch_bounds__(256) void k_prep(const float* __restrict__ lm_X,
    const float* __restrict__ lm_Y, const float* __restrict__ tg_X,
    const float* __restrict__ lm_delay, const float* __restrict__ Wq,
    const float* __restrict__ Wk, const float* __restrict__ g1p,
    const float* __restrict__ ap, const float* __restrict__ bp,
    __bf16* __restrict__ Kb, __bf16* __restrict__ Fzb,
    __bf16* __restrict__ Qb, float* __restrict__ rp) {
  const int bid = blockIdx.x;
  const int tid = threadIdx.x;
  if (bid < 157) {
    __shared__ float sX[64 * DIN];      // 7.5 KB
    __shared__ __bf16 sF[64][33];
    const int j0 = bid * 64;
    for (int idx = tid; idx < 64 * DIN; idx += 256) {
      const int g = j0 * DIN + idx;
      sX[idx] = (g < N1 * DIN) ? lm_X[g] : 0.f;
    }
    const int z = tid & 31, jl = tid >> 5;
    float wk[DIN];
#pragma unroll
    for (int k = 0; k < DIN; ++k) wk[k] = Wk[z * DIN + k];
    __syncthreads();
#pragma unroll
    for (int q8 = 0; q8 < 8; ++q8) {
      const int jj = jl + q8 * 8;
      const int j = j0 + jj;
      float s = 0.f;
#pragma unroll
      for (int k = 0; k < DIN; ++k) s = fmaf(sX[jj * DIN + k], wk[k], s);
      float fval;
      if (z < DIN) fval = sX[jj * DIN + z];
      else fval = (j < N1) ? lm_Y[j * 2 + (z - DIN)] : 0.f;
      if (j < N1P) Kb[j * DZ + z] = (__bf16)s;
      sF[jj][z] = (__bf16)fval;
    }
    __syncthreads();
    const int z2 = tid >> 3, sub = tid & 7;
    const int jbase = j0 + sub * 8;
    if (jbase < N1P) {
      bf16x8 v;
#pragma unroll
      for (int e = 0; e < 8; ++e) v[e] = sF[sub * 8 + e][z2];
      *(bf16x8*)(Fzb + (size_t)z2 * N1P + jbase) = v;
    }
  } else if (bid < 236) {
    __shared__ float sX[64 * DIN];
    const int i0 = (bid - 157) * 64;
    for (int idx = tid; idx < 64 * DIN; idx += 256) {
      const int g = i0 * DIN + idx;
      sX[idx] = (g < N2 * DIN) ? tg_X[g] : 0.f;
    }
    const int z = tid & 31, il = tid >> 5;
    float wq[DIN];
#pragma unroll
    for (int k = 0; k < DIN; ++k) wq[k] = Wq[z * DIN + k];
    __syncthreads();
    // fold 1/sqrt(32) * log2(e) so k_attn uses exp2 directly
    const float sc = 0.17677669529663687f * 1.4426950408889634f;
#pragma unroll
    for (int q8 = 0; q8 < 8; ++q8) {
      const int ii = il + q8 * 8;
      const int i = i0 + ii;
      float s = 0.f;
#pragma unroll
      for (int k = 0; k < DIN; ++k) s = fmaf(sX[ii * DIN + k], wq[k], s);
      if (i < N2P) Qb[i * DZ + z] = (__bf16)(s * sc);
    }
  } else {
    const int b3 = bid - 236;
    const int z = tid & 31, jg = tid >> 5;
    const float a = ap[0], b = bp[0], g1 = g1p[0];
    float rs = 0.f, dv = 0.f, dss = 0.f;
    for (int j = b3 * 8 + jg; j < N1; j += NRED * 8) {
      float f = (z < DIN) ? lm_X[j * DIN + z] : lm_Y[j * 2 + (z - DIN)];
      float ds = __expf(-g1 * (a * lm_delay[j] + b));
      rs += f; dv += ds * f;
      if (z == 0) dss += ds;
    }
    __shared__ float sb0[8][32], sb1[8][32], sd[8];
    sb0[jg][z] = rs; sb1[jg][z] = dv;
    if (z == 0) sd[jg] = dss;
    __syncthreads();
    if (tid < 32) {
      float t0 = 0.f, t1 = 0.f;
#pragma unroll
      for (int g = 0; g < 8; ++g) { t0 += sb0[g][tid]; t1 += sb1[g][tid]; }
      rp[b3 * 66 + tid] = t0;
      rp[b3 * 66 + 32 + tid] = t1;
    } else if (tid == 32) {
      float t = 0.f;
#pragma unroll
      for (int g = 0; g < 8; ++g) t += sd[g];
      rp[b3 * 66 + 64] = t;
    }
  }
}

// Single-pass attention. Per (i-tile, chunk-group) block: 4 waves = 4 j-chunks.
// sacc = (q*log2e/sqrt32)·k via MFMA; em1 = exp2(sacc)-1 (v_exp, trans pipe;
// zero pads -> em1=0 exactly); Zpart = sum em1; M1part = sum em1·F via MFMA.
// A-fragment repack via v_permlane32_swap (no DS ops).
__global__ __launch_bounds__(256) void k_attn(const __bf16* __restrict__ Kb,
    const __bf16* __restrict__ Fzb, const __bf16* __restrict__ Qb,
    float* __restrict__ Zp, __bf16* __restrict__ M1p) {
  __shared__ float sZ[4][32];
  __shared__ float sM[4][32][32];
  const int it = blockIdx.x / NCHB, cb = blockIdx.x % NCHB;
  const int i0 = it * 32;
  const int tid = threadIdx.x, lane = tid & 63, wid = tid >> 6;
  const int li = lane & 31, hi = lane >> 5;
  const int c = cb * 4 + wid;
  const int t0 = c * CTILES, t1 = min(t0 + CTILES, NTJ);
  const bf16x8 b0 = *(const bf16x8*)(Qb + (i0 + li) * DZ + hi * 8);
  const bf16x8 b1 = *(const bf16x8*)(Qb + (i0 + li) * DZ + 16 + hi * 8);
  float s1 = 0.f;
  f32x16 pacc = {0.f,0.f,0.f,0.f,0.f,0.f,0.f,0.f,0.f,0.f,0.f,0.f,0.f,0.f,0.f,0.f};
  for (int t = t0; t < t1; ++t) {
    const int jt = t * 32;
    bf16x8 a0 = *(const bf16x8*)(Kb + (jt + li) * DZ + hi * 8);
    bf16x8 a1 = *(const bf16x8*)(Kb + (jt + li) * DZ + 16 + hi * 8);
    bf16x8 fb0 = *(const bf16x8*)(Fzb + (size_t)li * N1P + jt + hi * 8);
    bf16x8 fb1 = *(const bf16x8*)(Fzb + (size_t)li * N1P + jt + 16 + hi * 8);
    f32x16 sacc = {0.f,0.f,0.f,0.f,0.f,0.f,0.f,0.f,0.f,0.f,0.f,0.f,0.f,0.f,0.f,0.f};
    sacc = __builtin_amdgcn_mfma_f32_32x32x16_bf16(a0, b0, sacc, 0, 0, 0);
    sacc = __builtin_amdgcn_mfma_f32_32x32x16_bf16(a1, b1, sacc, 0, 0, 0);
    unsigned u[8];
#pragma unroll
    for (int k2 = 0; k2 < 8; ++k2) {
      const float e0 = __builtin_amdgcn_exp2f(sacc[2 * k2]) - 1.f;
      const float e1 = __builtin_amdgcn_exp2f(sacc[2 * k2 + 1]) - 1.f;
      s1 += e0 + e1;
      u[k2] = pack2bf(e0, e1);
    }
    // repack D-layout (j rows interleaved across lane halves) -> A-frag,
    // equivalent to the shfl_xor(32)+select network but pure VALU:
    // swap(a,b): ret0=[a.lo|b.lo], ret1=[a.hi|b.hi]
    W4 A1, A2;
    u32x2 r01 = __builtin_amdgcn_permlane32_swap(u[0], u[2], false, false);
    u32x2 r23 = __builtin_amdgcn_permlane32_swap(u[1], u[3], false, false);
    u32x2 r45 = __builtin_amdgcn_permlane32_swap(u[4], u[6], false, false);
    u32x2 r67 = __builtin_amdgcn_permlane32_swap(u[5], u[7], false, false);
    A1.w[0] = r01[0]; A1.w[2] = r01[1];
    A1.w[1] = r23[0]; A1.w[3] = r23[1];
    A2.w[0] = r45[0]; A2.w[2] = r45[1];
    A2.w[1] = r67[0]; A2.w[3] = r67[1];
    pacc = __builtin_amdgcn_mfma_f32_32x32x16_bf16(A1.v, fb0, pacc, 0, 0, 0);
    pacc = __builtin_amdgcn_mfma_f32_32x32x16_bf16(A2.v, fb1, pacc, 0, 0, 0);
  }
  s1 += __shfl_xor(s1, 32, 64);
  if (hi == 0) sZ[wid][li] = s1;
#pragma unroll
  for (int r = 0; r < 16; ++r) {
    const int irow = (r & 3) + 8 * (r >> 2) + 4 * hi;
    sM[wid][irow][li] = pacc[r];
  }
  __syncthreads();
  if (tid < 32)
    Zp[cb * N2P + i0 + tid] = sZ[0][tid] + sZ[1][tid] + sZ[2][tid] + sZ[3][tid];
#pragma unroll
  for (int v = 0; v < 4; ++v) {
    const int idx = v * 256 + tid;
    const int row = idx >> 5, z = idx & 31;
    float m = sM[0][row][z] + sM[1][row][z] + sM[2][row][z] + sM[3][row][z];
    M1p[((size_t)cb * N2P + i0 + row) * DZ + z] = (__bf16)m;
  }
}

// Tail: reduce red partials, inline router, per-target matvecs + heads.
__global__ __launch_bounds__(256) void k_final(
    const float* __restrict__ tg_X, const float* __restrict__ tg_delay,
    const float* __restrict__ Zp, const __bf16* __restrict__ M1p,
    const float* __restrict__ rp,
    const float* __restrict__ W1, const float* __restrict__ b1,
    const float* __restrict__ W2, const float* __restrict__ b2,
    const float* __restrict__ Wg, const float* __restrict__ bg,
    const float* __restrict__ Wa, const float* __restrict__ ba,
    const float* __restrict__ g2p, const float* __restrict__ g3p,
    const float* __restrict__ ap, const float* __restrict__ bp,
    float* __restrict__ out) {
  __shared__ float s_a[8][DZ], s_t1[8][DZ], s_t2[8][DZ];
  __shared__ float s_rsum[DZ], s_dv[DZ], s_r0[DZ], s_r1[DZ], s_tmp[DZ];
  __shared__ float s_ds[1];
  const int tid = threadIdx.x;
  const int z = tid & 31, li = tid >> 5;
  const int i = blockIdx.x * 8 + li;
  if (tid < 32) {
    float t0 = 0.f, t1 = 0.f;
#pragma unroll
    for (int cc = 0; cc < NRED; ++cc) {
      t0 += rp[cc * 66 + tid];
      t1 += rp[cc * 66 + 32 + tid];
    }
    s_rsum[tid] = t0; s_dv[tid] = t1;
  } else if (tid == 32) {
    float d = 0.f;
#pragma unroll
    for (int cc = 0; cc < NRED; ++cc) d += rp[cc * 66 + 64];
    s_ds[0] = d;
  }
  __syncthreads();
  if (li == 0) {
    const float r0 = s_rsum[z] * (1.f / (float)N1);
    s_r0[z] = r0;
    s_tmp[z] = (r0 + s_dv[z]) / (1.f + s_ds[0] + 1e-12f);
  }
  __syncthreads();
  if (li == 0) {
    float acc = b1[z];
#pragma unroll
    for (int k = 0; k < DZ; ++k) acc += W1[z * DZ + k] * s_tmp[k];
    s_r1[z] = acc;
  }
  const float a = ap[0], b = bp[0], g2 = g2p[0], g3 = g3p[0];
  const float td = tg_delay[i];
  const float rt0 = __expf(-g2 * (a * td + b));
  const float rt1 = __expf(-g3 * (a * td + b));
  const float tgx = (z < DIN) ? tg_X[i * DIN + z] : 0.f;
  float Zt = (float)N1, m1 = 0.f;
#pragma unroll
  for (int cc = 0; cc < NCHB; ++cc) {
    Zt += Zp[cc * N2P + i];
    m1 += (float)M1p[((size_t)cc * N2P + i) * DZ + z];
  }
  const float rsum_z = s_rsum[z];
  const float aggsum = rsum_z + (m1 + rsum_z) / Zt;   // sum_j t_j F_j
  const float sum_t = (float)N1 + 1.f;                // sum_j t_j
  const float deg = 1.f + sum_t + rt0 + 1e-12f;
  __syncthreads();
  s_a[li][z] = (tgx + aggsum + rt0 * s_r0[z]) / deg;
  __syncthreads();
  float t1 = b1[z];
#pragma unroll
  for (int k = 0; k < DZ; ++k) t1 += W1[z * DZ + k] * s_a[li][k];
  s_t1[li][z] = t1;
  __syncthreads();
  s_a[li][z] = (t1 + rt1 * s_r1[z]) / (1.f + rt1 + 1e-12f);
  __syncthreads();
  float t2 = b2[z];
#pragma unroll
  for (int k = 0; k < DZ; ++k) t2 += W2[z * DZ + k] * s_a[li][k];
  s_t2[li][z] = t2;
  __syncthreads();
  if (z < 5) {
    float og = bg[z];
#pragma unroll
    for (int k = 0; k < DZ; ++k) og += Wg[z * 64 + k] * s_t1[li][k];
#pragma unroll
    for (int k = 0; k < DZ; ++k) og += Wg[z * 64 + DZ + k] * s_t2[li][k];
    if (z == 0)      out[2 * i] = og;
    else if (z == 1) out[2 * i + 1] = og;
    else if (z == 2) out[10000 + i] = softplus_f(og);
    else if (z == 3) out[15000 + i] = softplus_f(og) + 1.f;
    else             out[20000 + i] = softplus_f(og);
  } else if (z >= 8 && z < 13) {
    const int hh = z - 8;
    float oa = ba[hh];
#pragma unroll
    for (int k = 0; k < DIN; ++k) oa += Wa[hh * DIN + k] * tg_X[i * DIN + k];
    if (hh == 0)      out[25000 + 2 * i] = oa;
    else if (hh == 1) out[25000 + 2 * i + 1] = oa;
    else if (hh == 2) out[35000 + i] = softplus_f(oa);
    else if (hh == 3) out[40000 + i] = softplus_f(oa) + 1.f;
    else              out[45000 + i] = softplus_f(oa);
  }
}

extern "C" void kernel_launch(void* const* d_in, const int* in_sizes, int n_in,
                              void* d_out, int out_size, void* d_ws, size_t ws_size,
                              hipStream_t stream) {
  const float* lm_X    = (const float*)d_in[0];
  const float* lm_Y    = (const float*)d_in[1];
  const float* tg_X    = (const float*)d_in[2];
  const float* lm_delay= (const float*)d_in[4];
  const float* tg_delay= (const float*)d_in[5];
  const float* Wq      = (const float*)d_in[6];
  const float* Wk      = (const float*)d_in[7];
  const float* g1      = (const float*)d_in[9];
  const float* g2      = (const float*)d_in[10];
  const float* g3      = (const float*)d_in[11];
  const float* al      = (const float*)d_in[12];
  const float* be      = (const float*)d_in[13];
  const float* W1      = (const float*)d_in[14];
  const float* b1      = (const float*)d_in[15];
  const float* W2      = (const float*)d_in[16];
  const float* b2      = (const float*)d_in[17];
  const float* Wg      = (const float*)d_in[18];
  const float* bg      = (const float*)d_in[19];
  const float* Wa      = (const float*)d_in[20];
  const float* ba      = (const float*)d_in[21];
  float* out = (float*)d_out;
  char* ws   = (char*)d_ws;

  __bf16* Kb   = (__bf16*)(ws + OFFB_K);
  __bf16* Fzb  = (__bf16*)(ws + OFFB_FZ);
  __bf16* Qb   = (__bf16*)(ws + OFFB_Q);
  float*  Zp   = (float*)(ws + OFFB_ZP);
  __bf16* M1p  = (__bf16*)(ws + OFFB_M1);
  float*  rp   = (float*)(ws + OFFB_RP);

  hipLaunchKernelGGL(k_prep, dim3(252), dim3(256), 0, stream,
                     lm_X, lm_Y, tg_X, lm_delay, Wq, Wk, g1, al, be,
                     Kb, Fzb, Qb, rp);
  hipLaunchKernelGGL(k_attn, dim3(NTI * NCHB), dim3(256), 0, stream,
                     Kb, Fzb, Qb, Zp, M1p);
  hipLaunchKernelGGL(k_final, dim3(625), dim3(256), 0, stream,
                     tg_X, tg_delay, Zp, M1p, rp,
                     W1, b1, W2, b2, Wg, bg, Wa, ba, g2, g3, al, be, out);
}

// Round 7
// 56.059 us; speedup vs baseline: 1.0077x; 1.0077x over previous
//
#include <hip/hip_runtime.h>
#include <math.h>

#define N1 10000
#define N2 5000
#define DIN 30
#define DZ 32
#define N1P 10016   // 313*32
#define N2P 5024    // 157*32
#define NTJ 313     // j-tiles of 32
#define NTI 157     // i-tiles of 32
#define NCHB 8      // partial buffers per i-tile (blocks per i-tile)
#define CTILES 10   // j-tiles per wave-chunk (32 chunks; last has 3)
#define NRED 16     // landmark-reduction blocks

// byte offsets in ws (16B aligned)
#define OFFB_K    0u        // bf16 K[N1P][32]
#define OFFB_FF   641024u   // bf16 F_frag[(t,frag,lane)][8]  (MFMA B-frag order)
#define OFFB_Q    1282048u  // bf16 Qs[N2P][32]  (pre-scaled by log2e/sqrt(32))
#define OFFB_ZP   1603584u  // f32 Zpart[8][N2P] (sum of em1)
#define OFFB_M1   1764352u  // bf16 M1part[8][N2P][32]
#define OFFB_RP   7069696u  // f32 red_part[16][66]: rsum[32],dvec[32],ds_sum

typedef __bf16 bf16x8 __attribute__((ext_vector_type(8)));
typedef float f32x16 __attribute__((ext_vector_type(16)));
typedef unsigned u32x2 __attribute__((ext_vector_type(2)));

union W4 { unsigned w[4]; bf16x8 v; };

__device__ __forceinline__ float softplus_f(float x) {
  return fmaxf(x, 0.f) + log1pf(__expf(-fabsf(x)));
}
__device__ __forceinline__ unsigned pack2bf(float a, float b) {
  union { __bf16 h[2]; unsigned u; } x;
  x.h[0] = (__bf16)a; x.h[1] = (__bf16)b; return x.u;
}

// Fused prep. blocks [0,157): K + F_frag (64 lm rows each); [157,236): Q;
// [236,252): landmark reductions -> red_part (no atomics).
__global__ __launch_bounds__(256) void k_prep(const float* __restrict__ lm_X,
    const float* __restrict__ lm_Y, const float* __restrict__ tg_X,
    const float* __restrict__ lm_delay, const float* __restrict__ Wq,
    const float* __restrict__ Wk, const float* __restrict__ g1p,
    const float* __restrict__ ap, const float* __restrict__ bp,
    __bf16* __restrict__ Kb, __bf16* __restrict__ Ff,
    __bf16* __restrict__ Qb, float* __restrict__ rp) {
  const int bid = blockIdx.x;
  const int tid = threadIdx.x;
  if (bid < 157) {
    __shared__ float sX[64 * DIN];      // 7.5 KB
    __shared__ __bf16 sF[64][33];
    const int j0 = bid * 64;
    for (int idx = tid; idx < 64 * DIN; idx += 256) {
      const int g = j0 * DIN + idx;
      sX[idx] = (g < N1 * DIN) ? lm_X[g] : 0.f;
    }
    const int z = tid & 31, jl = tid >> 5;
    float wk[DIN];
#pragma unroll
    for (int k = 0; k < DIN; ++k) wk[k] = Wk[z * DIN + k];
    __syncthreads();
#pragma unroll
    for (int q8 = 0; q8 < 8; ++q8) {
      const int jj = jl + q8 * 8;
      const int j = j0 + jj;
      float s = 0.f;
#pragma unroll
      for (int k = 0; k < DIN; ++k) s = fmaf(sX[jj * DIN + k], wk[k], s);
      float fval;
      if (z < DIN) fval = sX[jj * DIN + z];
      else fval = (j < N1) ? lm_Y[j * 2 + (z - DIN)] : 0.f;
      if (j < N1P) Kb[j * DZ + z] = (__bf16)s;
      sF[jj][z] = (__bf16)fval;
    }
    __syncthreads();
    // F in MFMA B-fragment order: unit (t, frag, lane) holds
    // F[j = t*32 + frag*16 + (lane>>5)*8 + e][z = lane&31], e=0..7
    const int tt = tid >> 7, frag = (tid >> 6) & 1, lane = tid & 63;
    const int li2 = lane & 31, hi2 = lane >> 5;
    const int tglob = 2 * bid + tt;
    if (tglob < NTJ) {
      const int jl2 = tt * 32 + frag * 16 + hi2 * 8;
      bf16x8 v;
#pragma unroll
      for (int e = 0; e < 8; ++e) v[e] = sF[jl2 + e][li2];
      *(bf16x8*)(Ff + ((size_t)(tglob * 2 + frag) * 64 + lane) * 8) = v;
    }
  } else if (bid < 236) {
    __shared__ float sX[64 * DIN];
    const int i0 = (bid - 157) * 64;
    for (int idx = tid; idx < 64 * DIN; idx += 256) {
      const int g = i0 * DIN + idx;
      sX[idx] = (g < N2 * DIN) ? tg_X[g] : 0.f;
    }
    const int z = tid & 31, il = tid >> 5;
    float wq[DIN];
#pragma unroll
    for (int k = 0; k < DIN; ++k) wq[k] = Wq[z * DIN + k];
    __syncthreads();
    // fold 1/sqrt(32) * log2(e) so k_attn uses exp2 directly
    const float sc = 0.17677669529663687f * 1.4426950408889634f;
#pragma unroll
    for (int q8 = 0; q8 < 8; ++q8) {
      const int ii = il + q8 * 8;
      const int i = i0 + ii;
      float s = 0.f;
#pragma unroll
      for (int k = 0; k < DIN; ++k) s = fmaf(sX[ii * DIN + k], wq[k], s);
      if (i < N2P) Qb[i * DZ + z] = (__bf16)(s * sc);
    }
  } else {
    const int b3 = bid - 236;
    const int z = tid & 31, jg = tid >> 5;
    const float a = ap[0], b = bp[0], g1 = g1p[0];
    float rs = 0.f, dv = 0.f, dss = 0.f;
    for (int j = b3 * 8 + jg; j < N1; j += NRED * 8) {
      float f = (z < DIN) ? lm_X[j * DIN + z] : lm_Y[j * 2 + (z - DIN)];
      float ds = __expf(-g1 * (a * lm_delay[j] + b));
      rs += f; dv += ds * f;
      if (z == 0) dss += ds;
    }
    __shared__ float sb0[8][32], sb1[8][32], sd[8];
    sb0[jg][z] = rs; sb1[jg][z] = dv;
    if (z == 0) sd[jg] = dss;
    __syncthreads();
    if (tid < 32) {
      float t0 = 0.f, t1 = 0.f;
#pragma unroll
      for (int g = 0; g < 8; ++g) { t0 += sb0[g][tid]; t1 += sb1[g][tid]; }
      rp[b3 * 66 + tid] = t0;
      rp[b3 * 66 + 32 + tid] = t1;
    } else if (tid == 32) {
      float t = 0.f;
#pragma unroll
      for (int g = 0; g < 8; ++g) t += sd[g];
      rp[b3 * 66 + 64] = t;
    }
  }
}

// Single-pass attention. Per (i-tile, chunk-group) block: 4 waves = 4 j-chunks.
// All operand loads fully coalesced (K contiguous, F in fragment order);
// register double-buffer hides L2 latency under mfma->exp2->permlane chain.
__global__ __launch_bounds__(256) void k_attn(const __bf16* __restrict__ Kb,
    const __bf16* __restrict__ Ff, const __bf16* __restrict__ Qb,
    float* __restrict__ Zp, __bf16* __restrict__ M1p) {
  __shared__ float sZ[4][32];
  __shared__ float sM[4][32][32];
  const int it = blockIdx.x / NCHB, cb = blockIdx.x % NCHB;
  const int i0 = it * 32;
  const int tid = threadIdx.x, lane = tid & 63, wid = tid >> 6;
  const int li = lane & 31, hi = lane >> 5;
  const int c = cb * 4 + wid;
  const int t0 = c * CTILES, t1 = min(t0 + CTILES, NTJ);
  const bf16x8 b0 = *(const bf16x8*)(Qb + (i0 + li) * DZ + hi * 8);
  const bf16x8 b1 = *(const bf16x8*)(Qb + (i0 + li) * DZ + 16 + hi * 8);
  float s1 = 0.f;
  f32x16 pacc = {0.f,0.f,0.f,0.f,0.f,0.f,0.f,0.f,0.f,0.f,0.f,0.f,0.f,0.f,0.f,0.f};
  // preload tile t0
  bf16x8 a0 = *(const bf16x8*)(Kb + ((size_t)t0 * 32 + li) * DZ + hi * 8);
  bf16x8 a1 = *(const bf16x8*)(Kb + ((size_t)t0 * 32 + li) * DZ + 16 + hi * 8);
  bf16x8 f0 = *(const bf16x8*)(Ff + (size_t)t0 * 1024 + lane * 8);
  bf16x8 f1 = *(const bf16x8*)(Ff + (size_t)t0 * 1024 + 512 + lane * 8);
  for (int t = t0; t < t1; ++t) {
    bf16x8 na0 = a0, na1 = a1, nf0 = f0, nf1 = f1;
    if (t + 1 < t1) {
      const int jn = (t + 1) * 32;
      na0 = *(const bf16x8*)(Kb + ((size_t)jn + li) * DZ + hi * 8);
      na1 = *(const bf16x8*)(Kb + ((size_t)jn + li) * DZ + 16 + hi * 8);
      nf0 = *(const bf16x8*)(Ff + (size_t)(t + 1) * 1024 + lane * 8);
      nf1 = *(const bf16x8*)(Ff + (size_t)(t + 1) * 1024 + 512 + lane * 8);
    }
    f32x16 sacc = {0.f,0.f,0.f,0.f,0.f,0.f,0.f,0.f,0.f,0.f,0.f,0.f,0.f,0.f,0.f,0.f};
    sacc = __builtin_amdgcn_mfma_f32_32x32x16_bf16(a0, b0, sacc, 0, 0, 0);
    sacc = __builtin_amdgcn_mfma_f32_32x32x16_bf16(a1, b1, sacc, 0, 0, 0);
    unsigned u[8];
#pragma unroll
    for (int k2 = 0; k2 < 8; ++k2) {
      const float e0 = __builtin_amdgcn_exp2f(sacc[2 * k2]) - 1.f;
      const float e1 = __builtin_amdgcn_exp2f(sacc[2 * k2 + 1]) - 1.f;
      s1 += e0 + e1;
      u[k2] = pack2bf(e0, e1);
    }
    // repack D-layout -> A-frag via permlane32_swap (pure VALU)
    W4 A1, A2;
    u32x2 r01 = __builtin_amdgcn_permlane32_swap(u[0], u[2], false, false);
    u32x2 r23 = __builtin_amdgcn_permlane32_swap(u[1], u[3], false, false);
    u32x2 r45 = __builtin_amdgcn_permlane32_swap(u[4], u[6], false, false);
    u32x2 r67 = __builtin_amdgcn_permlane32_swap(u[5], u[7], false, false);
    A1.w[0] = r01[0]; A1.w[2] = r01[1];
    A1.w[1] = r23[0]; A1.w[3] = r23[1];
    A2.w[0] = r45[0]; A2.w[2] = r45[1];
    A2.w[1] = r67[0]; A2.w[3] = r67[1];
    pacc = __builtin_amdgcn_mfma_f32_32x32x16_bf16(A1.v, f0, pacc, 0, 0, 0);
    pacc = __builtin_amdgcn_mfma_f32_32x32x16_bf16(A2.v, f1, pacc, 0, 0, 0);
    a0 = na0; a1 = na1; f0 = nf0; f1 = nf1;
  }
  s1 += __shfl_xor(s1, 32, 64);
  if (hi == 0) sZ[wid][li] = s1;
#pragma unroll
  for (int r = 0; r < 16; ++r) {
    const int irow = (r & 3) + 8 * (r >> 2) + 4 * hi;
    sM[wid][irow][li] = pacc[r];
  }
  __syncthreads();
  if (tid < 32)
    Zp[cb * N2P + i0 + tid] = sZ[0][tid] + sZ[1][tid] + sZ[2][tid] + sZ[3][tid];
#pragma unroll
  for (int v = 0; v < 4; ++v) {
    const int idx = v * 256 + tid;
    const int row = idx >> 5, z = idx & 31;
    float m = sM[0][row][z] + sM[1][row][z] + sM[2][row][z] + sM[3][row][z];
    M1p[((size_t)cb * N2P + i0 + row) * DZ + z] = (__bf16)m;
  }
}

// Tail: reduce red partials, inline router, per-target matvecs + heads.
__global__ __launch_bounds__(256) void k_final(
    const float* __restrict__ tg_X, const float* __restrict__ tg_delay,
    const float* __restrict__ Zp, const __bf16* __restrict__ M1p,
    const float* __restrict__ rp,
    const float* __restrict__ W1, const float* __restrict__ b1,
    const float* __restrict__ W2, const float* __restrict__ b2,
    const float* __restrict__ Wg, const float* __restrict__ bg,
    const float* __restrict__ Wa, const float* __restrict__ ba,
    const float* __restrict__ g2p, const float* __restrict__ g3p,
    const float* __restrict__ ap, const float* __restrict__ bp,
    float* __restrict__ out) {
  __shared__ float s_a[8][DZ], s_t1[8][DZ], s_t2[8][DZ];
  __shared__ float s_rsum[DZ], s_dv[DZ], s_r0[DZ], s_r1[DZ], s_tmp[DZ];
  __shared__ float s_ds[1];
  const int tid = threadIdx.x;
  const int z = tid & 31, li = tid >> 5;
  const int i = blockIdx.x * 8 + li;
  if (tid < 32) {
    float t0 = 0.f, t1 = 0.f;
#pragma unroll
    for (int cc = 0; cc < NRED; ++cc) {
      t0 += rp[cc * 66 + tid];
      t1 += rp[cc * 66 + 32 + tid];
    }
    s_rsum[tid] = t0; s_dv[tid] = t1;
  } else if (tid == 32) {
    float d = 0.f;
#pragma unroll
    for (int cc = 0; cc < NRED; ++cc) d += rp[cc * 66 + 64];
    s_ds[0] = d;
  }
  __syncthreads();
  if (li == 0) {
    const float r0 = s_rsum[z] * (1.f / (float)N1);
    s_r0[z] = r0;
    s_tmp[z] = (r0 + s_dv[z]) / (1.f + s_ds[0] + 1e-12f);
  }
  __syncthreads();
  if (li == 0) {
    float acc = b1[z];
#pragma unroll
    for (int k = 0; k < DZ; ++k) acc += W1[z * DZ + k] * s_tmp[k];
    s_r1[z] = acc;
  }
  const float a = ap[0], b = bp[0], g2 = g2p[0], g3 = g3p[0];
  const float td = tg_delay[i];
  const float rt0 = __expf(-g2 * (a * td + b));
  const float rt1 = __expf(-g3 * (a * td + b));
  const float tgx = (z < DIN) ? tg_X[i * DIN + z] : 0.f;
  float Zt = (float)N1, m1 = 0.f;
#pragma unroll
  for (int cc = 0; cc < NCHB; ++cc) {
    Zt += Zp[cc * N2P + i];
    m1 += (float)M1p[((size_t)cc * N2P + i) * DZ + z];
  }
  const float rsum_z = s_rsum[z];
  const float aggsum = rsum_z + (m1 + rsum_z) / Zt;   // sum_j t_j F_j
  const float sum_t = (float)N1 + 1.f;                // sum_j t_j
  const float deg = 1.f + sum_t + rt0 + 1e-12f;
  __syncthreads();
  s_a[li][z] = (tgx + aggsum + rt0 * s_r0[z]) / deg;
  __syncthreads();
  float t1 = b1[z];
#pragma unroll
  for (int k = 0; k < DZ; ++k) t1 += W1[z * DZ + k] * s_a[li][k];
  s_t1[li][z] = t1;
  __syncthreads();
  s_a[li][z] = (t1 + rt1 * s_r1[z]) / (1.f + rt1 + 1e-12f);
  __syncthreads();
  float t2 = b2[z];
#pragma unroll
  for (int k = 0; k < DZ; ++k) t2 += W2[z * DZ + k] * s_a[li][k];
  s_t2[li][z] = t2;
  __syncthreads();
  if (z < 5) {
    float og = bg[z];
#pragma unroll
    for (int k = 0; k < DZ; ++k) og += Wg[z * 64 + k] * s_t1[li][k];
#pragma unroll
    for (int k = 0; k < DZ; ++k) og += Wg[z * 64 + DZ + k] * s_t2[li][k];
    if (z == 0)      out[2 * i] = og;
    else if (z == 1) out[2 * i + 1] = og;
    else if (z == 2) out[10000 + i] = softplus_f(og);
    else if (z == 3) out[15000 + i] = softplus_f(og) + 1.f;
    else             out[20000 + i] = softplus_f(og);
  } else if (z >= 8 && z < 13) {
    const int hh = z - 8;
    float oa = ba[hh];
#pragma unroll
    for (int k = 0; k < DIN; ++k) oa += Wa[hh * DIN + k] * tg_X[i * DIN + k];
    if (hh == 0)      out[25000 + 2 * i] = oa;
    else if (hh == 1) out[25000 + 2 * i + 1] = oa;
    else if (hh == 2) out[35000 + i] = softplus_f(oa);
    else if (hh == 3) out[40000 + i] = softplus_f(oa) + 1.f;
    else              out[45000 + i] = softplus_f(oa);
  }
}

extern "C" void kernel_launch(void* const* d_in, const int* in_sizes, int n_in,
                              void* d_out, int out_size, void* d_ws, size_t ws_size,
                              hipStream_t stream) {
  const float* lm_X    = (const float*)d_in[0];
  const float* lm_Y    = (const float*)d_in[1];
  const float* tg_X    = (const float*)d_in[2];
  const float* lm_delay= (const float*)d_in[4];
  const float* tg_delay= (const float*)d_in[5];
  const float* Wq      = (const float*)d_in[6];
  const float* Wk      = (const float*)d_in[7];
  const float* g1      = (const float*)d_in[9];
  const float* g2      = (const float*)d_in[10];
  const float* g3      = (const float*)d_in[11];
  const float* al      = (const float*)d_in[12];
  const float* be      = (const float*)d_in[13];
  const float* W1      = (const float*)d_in[14];
  const float* b1      = (const float*)d_in[15];
  const float* W2      = (const float*)d_in[16];
  const float* b2      = (const float*)d_in[17];
  const float* Wg      = (const float*)d_in[18];
  const float* bg      = (const float*)d_in[19];
  const float* Wa      = (const float*)d_in[20];
  const float* ba      = (const float*)d_in[21];
  float* out = (float*)d_out;
  char* ws   = (char*)d_ws;

  __bf16* Kb   = (__bf16*)(ws + OFFB_K);
  __bf16* Ff   = (__bf16*)(ws + OFFB_FF);
  __bf16* Qb   = (__bf16*)(ws + OFFB_Q);
  float*  Zp   = (float*)(ws + OFFB_ZP);
  __bf16* M1p  = (__bf16*)(ws + OFFB_M1);
  float*  rp   = (float*)(ws + OFFB_RP);

  hipLaunchKernelGGL(k_prep, dim3(252), dim3(256), 0, stream,
                     lm_X, lm_Y, tg_X, lm_delay, Wq, Wk, g1, al, be,
                     Kb, Ff, Qb, rp);
  hipLaunchKernelGGL(k_attn, dim3(NTI * NCHB), dim3(256), 0, stream,
                     Kb, Ff, Qb, Zp, M1p);
  hipLaunchKernelGGL(k_final, dim3(625), dim3(256), 0, stream,
                     tg_X, tg_delay, Zp, M1p, rp,
                     W1, b1, W2, b2, Wg, bg, Wa, ba, g2, g3, al, be, out);
}